// Round 11
// baseline (265.298 us; speedup 1.0000x reference)
//
#include <hip/hip_runtime.h>
#include <math.h>

// MADE autoregressive sampler, incremental-by-degree, v10.
// B=8192, D=64, CTX=256, H=512. Units sorted by degree (mh = h%63+1).
// v10 = v9 phase structure with 512-thread blocks / 16 rows / 1 unit per
// thread: same total FMA per CU (2 blocks x 8 waves = 16 waves/CU) but half
// the barrier instances per row, half the Wq load instructions per thread,
// and E/publish serial tails amortized over 16 rows. Weight layouts and prep
// are byte-identical to v9 (consumer-packed Wq[i][q][12], Woq[i][j][20]).
// launch_bounds(512,2) caps VGPR at 256 to avoid v9's 64-VGPR clamp + spill.

typedef float f2 __attribute__((ext_vector_type(2)));

#define Bn 8192
#define Dn 64
#define CTXn 256
#define Hn 512
#define On 128
#define Rn 16                    // rows per block

#define WQ_SZ  (64 * 512 * 12)   // 393216
#define WOQ_SZ (64 * 64 * 20)    //  81920
#define WCP_SZ (CTXn * Hn)       // 131072

// sorted index p -> original hidden unit h, and its degree k.
__device__ __forceinline__ int perm_of(int p, int* degout) {
  int k, t;
  if (p < 72) { k = p / 9 + 1; t = p - (k - 1) * 9; }
  else        { int pp = p - 72; k = pp / 8 + 9; t = pp - (k - 9) * 8; }
  *degout = k;
  return (k - 1) + 63 * t;
}

// ---------------- prep (identical to v9) ------------------------------------
__global__ void prep_kernel(const float* __restrict__ W1, const float* __restrict__ Wc,
                            const float* __restrict__ W2, const float* __restrict__ Wo,
                            const float* __restrict__ b1, const float* __restrict__ b2,
                            float* __restrict__ Wq, float* __restrict__ Woq,
                            float* __restrict__ WcpT, float* __restrict__ b1p,
                            float* __restrict__ b2p) {
  int idx = blockIdx.x * 256 + threadIdx.x;
  if (idx < WQ_SZ) {
    int i = idx / 6144, rem = idx - i * 6144;
    int q = rem / 12, e = rem - q * 12;
    int sb = (i < 8) ? 9 * i : 8 * i + 8;          // S_of(i+1)
    int c  = (i == 63) ? 0 : ((i < 8) ? 9 : 8);
    int dq; int hq = perm_of(q, &dq);
    float v = 0.f;
    if (e < 9) {
      if (e < c && dq >= i + 1) {                  // M2: deg_out >= i+1
        int dp; int hp = perm_of(sb + e, &dp);
        v = W2[hq * Hn + hp];
      }
    } else if (e == 9) {
      if (dq >= i + 1) v = W1[hq * Dn + i];        // M1 incl diagonal
    }
    Wq[idx] = v;
  } else if (idx < WQ_SZ + WOQ_SZ) {
    int jj = idx - WQ_SZ;
    int i = jj / 1280, rem = jj - i * 1280;
    int j = rem / 20, e = rem - j * 20;
    int sb = (i < 8) ? 9 * i : 8 * i + 8;
    int c  = (i == 63) ? 0 : ((i < 8) ? 9 : 8);
    float v = 0.f;
    int p = -1, o = 0;
    if (e < 9)                  { p = e;      o = j; }
    else if (e >= 10 && e < 19) { p = e - 10; o = j + 64; }
    if (p >= 0 && p < c && j >= i + 1) {           // Mo: (o&63) >= i+1
      int dp; int hp = perm_of(sb + p, &dp);
      v = Wo[o * Hn + hp];
    }
    Woq[jj] = v;
  } else if (idx < WQ_SZ + WOQ_SZ + WCP_SZ) {
    int jj = idx - (WQ_SZ + WOQ_SZ);
    int cc = jj >> 9, q = jj & 511;
    int dq; int hq = perm_of(q, &dq);
    WcpT[jj] = Wc[hq * CTXn + cc];
  } else if (idx < WQ_SZ + WOQ_SZ + WCP_SZ + 512) {
    int q = idx - (WQ_SZ + WOQ_SZ + WCP_SZ);
    int dq; int hq = perm_of(q, &dq);
    b1p[q] = b1[hq];
  } else if (idx < WQ_SZ + WOQ_SZ + WCP_SZ + 1024) {
    int q = idx - (WQ_SZ + WOQ_SZ + WCP_SZ + 512);
    int dq; int hq = perm_of(q, &dq);
    b2p[q] = b2[hq];
  }
}

// ---------------- main fused kernel ------------------------------------------
__global__ __launch_bounds__(512, 2)
void made_pk_kernel(
    const float* __restrict__ context, const float* __restrict__ WcpT,
    const float* __restrict__ b1p,
    const float* __restrict__ Wq, const float* __restrict__ Woq,
    const float* __restrict__ b2p, const float* __restrict__ bo,
    const float* __restrict__ eps, float* __restrict__ out) {
  __shared__ __align__(16) float ctxR[Rn][264];   // 16.9 KB
  __shared__ __align__(16) float zcur[Rn];
  __shared__ __align__(16) float h1g[9][Rn];
  __shared__ __align__(16) float h2g[9][Rn];

  int t = threadIdx.x;
  int b0 = blockIdx.x * Rn;
  int q = t;                               // owned sorted unit (1 per thread)
  int l = t & 63, rp = t >> 6;             // col-pair l; rows 2rp, 2rp+1 (rp 0..7)

  int fstep = (q < 72) ? q / 9 : (q - 72) / 8 + 8;   // finalize step of unit q
  int qm = t | 63;                                    // wave's max unit
  int gmax = __builtin_amdgcn_readfirstlane(
      (qm < 72) ? qm / 9 : (qm - 72) / 8 + 8);

  // ---- stage ctx ----
  for (int idx = t; idx < Rn * CTXn; idx += 512) {
    int r = idx >> 8, cc = idx & 255;
    ctxR[r][cc] = context[(b0 + r) * CTXn + cc];
  }
  __syncthreads();

  // ---- ctx GEMM: two 8-row passes (keeps xr pressure at 32 regs) ----
  float acc[Rn];
  {
    float bias = b1p[q];
    #pragma unroll
    for (int r = 0; r < Rn; ++r) acc[r] = bias;
  }
  #pragma clang loop unroll(disable)
  for (int half = 0; half < 2; ++half) {
    const float* wc = WcpT;
    #pragma clang loop unroll(disable)
    for (int c4 = 0; c4 < CTXn / 4; ++c4) {
      float xr[8][4];
      #pragma unroll
      for (int r = 0; r < 8; ++r) {
        float4 x = *(const float4*)&ctxR[8 * half + r][4 * c4];
        xr[r][0] = x.x; xr[r][1] = x.y; xr[r][2] = x.z; xr[r][3] = x.w;
      }
      #pragma unroll
      for (int k = 0; k < 4; ++k) {
        float w0 = wc[q];
        #pragma unroll
        for (int r = 0; r < 8; ++r)
          acc[8 * half + r] = fmaf(xr[r][k], w0, acc[8 * half + r]);
        wc += Hn;
      }
    }
  }

  // ---- pack state into f2 row-pairs ----
  f2 a1[8], a2[8];
  #pragma unroll
  for (int r2 = 0; r2 < 8; ++r2) a1[r2] = (f2){acc[2 * r2], acc[2 * r2 + 1]};
  {
    float bb = b2p[q];
    #pragma unroll
    for (int r2 = 0; r2 < 8; ++r2) a2[r2] = (f2){bb, bb};
  }
  f2 ocA = (f2){bo[l], bo[l]};             // col l, rows (2rp, 2rp+1)
  f2 ocB = (f2){bo[l + 64], bo[l + 64]};
  f2 ez2 = (f2){eps[(b0 + 2 * rp) * Dn + l], eps[(b0 + 2 * rp + 1) * Dn + l]};
  f2 zs = (f2){0.f, 0.f}, mus = zs, scs = zs;

  const float* wqp = Wq + (size_t)q * 12;
  const float* wopp = Woq + (size_t)l * 20;

  // ---- sequential loop: 3 barriers/step (must stay rolled) ----
  #pragma clang loop unroll(disable)
  for (int i = 0; i < Dn; ++i) {
    // E: thread (rp, l==i) finalizes cols (i, 64+i) for rows 2rp,2rp+1
    if (l == i) {
      f2 pre = ocB;
      float sx = fmaxf(pre.x, 0.f) + __logf(1.f + __expf(-fabsf(pre.x)));
      float sy = fmaxf(pre.y, 0.f) + __logf(1.f + __expf(-fabsf(pre.y)));
      f2 sc = (f2){sx, sy};
      f2 z = ocA + sc * ez2;
      *(f2*)&zcur[2 * rp] = z;
      zs = z; mus = ocA; scs = sc;
    }
    __syncthreads();                               // bar1: z published

    int sb = (i < 8) ? 9 * i : 8 * i + 8;          // group-i base
    bool live = (i <= gmax);                       // wave-uniform
    float4 A0, A1, A2;
    if (live) {
      const float4* a4 = (const float4*)wqp;       // 3 b128, imm offsets
      A0 = a4[0]; A1 = a4[1]; A2 = a4[2];
      float4 za = *(const float4*)&zcur[0];
      float4 zb = *(const float4*)&zcur[4];
      float4 zc_ = *(const float4*)&zcur[8];
      float4 zd = *(const float4*)&zcur[12];
      f2 zc[8] = {(f2){za.x, za.y}, (f2){za.z, za.w},
                  (f2){zb.x, zb.y}, (f2){zb.z, zb.w},
                  (f2){zc_.x, zc_.y}, (f2){zc_.z, zc_.w},
                  (f2){zd.x, zd.y}, (f2){zd.z, zd.w}};
      // FA: a1 += z_i * W1 (slot [9] = A2.y; zero-masked incl. finalized)
      f2 wv = (f2){A2.y, A2.y};
      #pragma unroll
      for (int r2 = 0; r2 < 8; ++r2) a1[r2] += wv * zc[r2];
      if (fstep == i) {
        int pp = q - sb;
        #pragma unroll
        for (int r2 = 0; r2 < 8; ++r2) {
          f2 h = (f2){fmaxf(a1[r2].x, 0.f), fmaxf(a1[r2].y, 0.f)};
          *(f2*)&h1g[pp][2 * r2] = h;
        }
      }
    }
    __syncthreads();                               // bar2: h1 published

    // Woq prefetch (consumed in D after bar3 -> drains at anyway-barrier)
    const float4* w4 = (const float4*)wopp;
    float4 B0 = w4[0], B1 = w4[1], B2 = w4[2], B3 = w4[3], B4 = w4[4];

    if (live) {
      float wA[9] = {A0.x, A0.y, A0.z, A0.w, A1.x, A1.y, A1.z, A1.w, A2.x};
      #pragma unroll
      for (int p = 0; p < 9; ++p) {
        float4 ha = *(const float4*)&h1g[p][0];    // broadcast reads
        float4 hb = *(const float4*)&h1g[p][4];
        float4 hc = *(const float4*)&h1g[p][8];
        float4 hd = *(const float4*)&h1g[p][12];
        f2 h[8] = {(f2){ha.x, ha.y}, (f2){ha.z, ha.w},
                   (f2){hb.x, hb.y}, (f2){hb.z, hb.w},
                   (f2){hc.x, hc.y}, (f2){hc.z, hc.w},
                   (f2){hd.x, hd.y}, (f2){hd.z, hd.w}};
        f2 wv = (f2){wA[p], wA[p]};
        #pragma unroll
        for (int r2 = 0; r2 < 8; ++r2) a2[r2] += wv * h[r2];
      }
      if (fstep == i) {
        int pp = q - sb;
        #pragma unroll
        for (int r2 = 0; r2 < 8; ++r2) {
          f2 h = (f2){fmaxf(a2[r2].x, 0.f), fmaxf(a2[r2].y, 0.f)};
          *(f2*)&h2g[pp][2 * r2] = h;
        }
      }
    }
    __syncthreads();                               // bar3: h2 published

    // D: oacc += h2 . Wog (zero-padded for cols <= i -> branch-free)
    {
      float wBa[9] = {B0.x, B0.y, B0.z, B0.w, B1.x, B1.y, B1.z, B1.w, B2.x};
      float wBb[9] = {B2.z, B2.w, B3.x, B3.y, B3.z, B3.w, B4.x, B4.y, B4.z};
      #pragma unroll
      for (int p = 0; p < 9; ++p) {
        f2 h = *(const f2*)&h2g[p][2 * rp];        // b64 read (wave-varying rp? no: rp uniform per wave)
        ocA += (f2){wBa[p], wBa[p]} * h;
        ocB += (f2){wBb[p], wBb[p]} * h;
      }
    }
    wqp += 6144; wopp += 1280;
  }

  // ---- epilogue: thread (rp,l) holds z/mu/sc for rows 2rp,2rp+1 col l ----
  out[(b0 + 2 * rp) * Dn + l] = zs.x;
  out[(b0 + 2 * rp + 1) * Dn + l] = zs.y;
  out[Bn * Dn + (b0 + 2 * rp) * Dn + l] = mus.x;
  out[Bn * Dn + (b0 + 2 * rp + 1) * Dn + l] = mus.y;
  out[2 * Bn * Dn + (b0 + 2 * rp) * Dn + l] = scs.x;
  out[2 * Bn * Dn + (b0 + 2 * rp + 1) * Dn + l] = scs.y;
}

extern "C" void kernel_launch(void* const* d_in, const int* in_sizes, int n_in,
                              void* d_out, int out_size, void* d_ws, size_t ws_size,
                              hipStream_t stream) {
  const float* context = (const float*)d_in[0];
  const float* eps     = (const float*)d_in[1];
  const float* W1      = (const float*)d_in[2];
  const float* b1      = (const float*)d_in[3];
  const float* Wc      = (const float*)d_in[4];
  const float* W2      = (const float*)d_in[5];
  const float* b2      = (const float*)d_in[6];
  const float* Wo      = (const float*)d_in[7];
  const float* bo      = (const float*)d_in[8];
  float* out = (float*)d_out;

  float* ws   = (float*)d_ws;
  float* Wq   = ws;                        // 393216 floats
  float* Woq  = Wq + WQ_SZ;                //  81920
  float* WcpT = Woq + WOQ_SZ;              // 131072
  float* b1p  = WcpT + WCP_SZ;             //    512
  float* b2p  = b1p + 512;                 //    512
  // total ws use: ~2.4 MB (L2-resident)

  int prep_elems = WQ_SZ + WOQ_SZ + WCP_SZ + 1024;
  prep_kernel<<<(prep_elems + 255) / 256, 256, 0, stream>>>(
      W1, Wc, W2, Wo, b1, b2, Wq, Woq, WcpT, b1p, b2p);
  made_pk_kernel<<<Bn / Rn, 512, 0, stream>>>(context, WcpT, b1p, Wq, Woq,
                                              b2p, bo, eps, out);
}